// Round 12
// baseline (997.687 us; speedup 1.0000x reference)
//
#include <hip/hip_runtime.h>

// LowRankAttention: B=2,H=12 (BH=24), S=8192, D=64, RANK=16, 10 steps, fp32.
// R11 structure + launch_bounds(256,5) + matrices in high LDS (one fewer barrier).
#define S_ 8192
#define D_ 64
#define BH_ 24

static constexpr float INV_S2 = 1.0f / (8192.0f * 8192.0f);
static constexpr float STEPSZ = 1000.0f;
static constexpr float CC = 2.0f * INV_S2;

#define LP_N (BH_ * S_ * 16)
#define PART_STRIDE 2576   // L: LQ[a*16+l] 0..1023, LL[l*16+c] 1024..1279; R-side +1280; N 2560
#define PART_N (BH_ * 32 * PART_STRIDE)
#define ACCF_STRIDE 2624   // MLL 0, MLQT[a*16+k] 256, RRS 1280, KRT[a*16+l] 1536, C1 2560, C2 2576, SRN 2592
#define ACCF_N (BH_ * ACCF_STRIDE)
#define PART2_STRIDE 1040  // RV[d*16+l] 0..1023, N 1024
#define PART2_N (BH_ * 32 * PART2_STRIDE)

// LDS map (floats): ST 0..5119 (stage 256x20); aQ dump overlays 0..4223;
// RDs 5120..6271 (mini dump); matrices (MODE>=1) 5120..6447 (dead before RDs).
#define MAT_OFF 5120
#define B_FLOATS 6448

// ---------------------------------------------------------------------------
// Low-VGPR block reduction over 256 rows. KIND 0: LQ+LL; 1: KR+RR+N; 2: RV+N.
// Phase 1 (mini): tc-scheme LL/RR + N (aX[16]+aN[16]) -> RDs.
// Phase 2 (main): lane owns column pair a=2*(t&31); aQ0/aQ1 (32 regs);
//   one shfl_xor(32); dump overlays ST after the post-main barrier.
// ---------------------------------------------------------------------------
template <int KIND>
__device__ __forceinline__ void reduceSide(const float* __restrict__ sb, int jbase, int t,
                                           const float* vals, float* B,
                                           float* __restrict__ pbase) {
  const int lane = t & 63, w = t >> 6;
  float* ST = B;
  float* RDs = B + MAT_OFF;        // 4 waves x 288 = 1152
  {
    float4* st = (float4*)(ST + t * 20);
    st[0] = make_float4(vals[0], vals[1], vals[2], vals[3]);
    st[1] = make_float4(vals[4], vals[5], vals[6], vals[7]);
    st[2] = make_float4(vals[8], vals[9], vals[10], vals[11]);
    st[3] = make_float4(vals[12], vals[13], vals[14], vals[15]);
  }
  __syncthreads();

  // ---- phase 1: mini loop ----
  {
    const int tcx = t & 15;
    float aX[16], aN[16];
#pragma unroll
    for (int l = 0; l < 16; ++l) { aX[l] = 0.f; aN[l] = 0.f; }
#pragma unroll 4
    for (int it = 0; it < 16; ++it) {
      const int jl = (t >> 4) + (it << 4);
      const float4* Vw = (const float4*)(ST + jl * 20);
      float4 b0 = Vw[0], b1 = Vw[1], b2 = Vw[2], b3 = Vw[3];
      float Vv[16] = {b0.x,b0.y,b0.z,b0.w, b1.x,b1.y,b1.z,b1.w,
                      b2.x,b2.y,b2.z,b2.w, b3.x,b3.y,b3.z,b3.w};
      float xc = (KIND < 2) ? ST[jl * 20 + tcx] : 0.f;
#pragma unroll
      for (int l = 0; l < 16; ++l) {
        if (KIND < 2) aX[l] += Vv[l] * xc;
        if (KIND >= 1) aN[l] += Vv[l];
      }
    }
#pragma unroll
    for (int l = 0; l < 16; ++l) {
      if (KIND < 2) { float v = aX[l]; v += __shfl_xor(v, 16); v += __shfl_xor(v, 32); aX[l] = v; }
      if (KIND >= 1) { float v = aN[l]; v += __shfl_xor(v, 16); v += __shfl_xor(v, 32); aN[l] = v; }
    }
    if (KIND < 2 && lane < 16) {
      float* p = RDs + w * 288 + lane * 17;
#pragma unroll
      for (int l = 0; l < 16; ++l) p[l] = aX[l];
    }
    if (KIND >= 1 && lane == 0) {
      float* p = RDs + w * 288 + 272;
#pragma unroll
      for (int l = 0; l < 16; ++l) p[l] = aN[l];
    }
  }

  // ---- phase 2: main pair loop ----
  float aQ0[16], aQ1[16];
#pragma unroll
  for (int l = 0; l < 16; ++l) { aQ0[l] = 0.f; aQ1[l] = 0.f; }
  {
    const int p2 = t & 31, slot8 = t >> 5;
    const float* srow = sb + (size_t)jbase * D_ + (p2 << 1);
#pragma unroll 4
    for (int it = 0; it < 32; ++it) {
      const int jl = slot8 + (it << 3);
      const float4* Vw = (const float4*)(ST + jl * 20);
      float4 b0 = Vw[0], b1 = Vw[1], b2 = Vw[2], b3 = Vw[3];
      float2 qq = *(const float2*)(srow + (size_t)jl * D_);
      aQ0[0]  += qq.x * b0.x; aQ1[0]  += qq.y * b0.x;
      aQ0[1]  += qq.x * b0.y; aQ1[1]  += qq.y * b0.y;
      aQ0[2]  += qq.x * b0.z; aQ1[2]  += qq.y * b0.z;
      aQ0[3]  += qq.x * b0.w; aQ1[3]  += qq.y * b0.w;
      aQ0[4]  += qq.x * b1.x; aQ1[4]  += qq.y * b1.x;
      aQ0[5]  += qq.x * b1.y; aQ1[5]  += qq.y * b1.y;
      aQ0[6]  += qq.x * b1.z; aQ1[6]  += qq.y * b1.z;
      aQ0[7]  += qq.x * b1.w; aQ1[7]  += qq.y * b1.w;
      aQ0[8]  += qq.x * b2.x; aQ1[8]  += qq.y * b2.x;
      aQ0[9]  += qq.x * b2.y; aQ1[9]  += qq.y * b2.y;
      aQ0[10] += qq.x * b2.z; aQ1[10] += qq.y * b2.z;
      aQ0[11] += qq.x * b2.w; aQ1[11] += qq.y * b2.w;
      aQ0[12] += qq.x * b3.x; aQ1[12] += qq.y * b3.x;
      aQ0[13] += qq.x * b3.y; aQ1[13] += qq.y * b3.y;
      aQ0[14] += qq.x * b3.z; aQ1[14] += qq.y * b3.z;
      aQ0[15] += qq.x * b3.w; aQ1[15] += qq.y * b3.w;
    }
  }
#pragma unroll
  for (int l = 0; l < 16; ++l) {
    aQ0[l] += __shfl_xor(aQ0[l], 32);
    aQ1[l] += __shfl_xor(aQ1[l], 32);
  }
  __syncthreads();   // all ST reads done; overlay aQ dump
  if (lane < 32) {
    float* g = B + w * 1056 + lane * 33;
#pragma unroll
    for (int l = 0; l < 16; ++l) { g[l] = aQ0[l]; g[16 + l] = aQ1[l]; }
  }
  __syncthreads();
#pragma unroll
  for (int r = 0; r < 4; ++r) {
    int o = t + r * 256;
    int a = o >> 4, l = o & 15;
    int idx = (a >> 1) * 33 + ((a & 1) << 4) + l;
    pbase[a * 16 + l] = B[idx] + B[1056 + idx] + B[2112 + idx] + B[3168 + idx];
  }
  if (KIND < 2) {
    int c = t >> 4, l = t & 15;
    int idx = MAT_OFF + c * 17 + l;
    pbase[1024 + l * 16 + c] = B[idx] + B[288 + idx] + B[576 + idx] + B[864 + idx];
  }
  if (KIND >= 1 && t < 16) {
    int idx = MAT_OFF + 272 + t;
    pbase[(KIND == 1 ? 1280 : 1024) + t] =
        B[idx] + B[288 + idx] + B[576 + idx] + B[864 + idx];
  }
  __syncthreads();
}

// M: RRS[k][l] (256) + KRT[a*16+l] (1024)
__device__ __forceinline__ void rowUpdate(const float* M, const float4* q4, float lv[16]) {
  const float4* RR4 = (const float4*)M;
  float n2 = 0.f;
#pragma unroll
  for (int l = 0; l < 16; ++l) n2 += lv[l] * lv[l];
  float ri = rsqrtf(n2);
  float r2 = ri * ri;
  float L[16];
#pragma unroll
  for (int l = 0; l < 16; ++l) L[l] = lv[l] * lv[l] * r2;
  float dl[16];
#pragma unroll
  for (int l = 0; l < 16; ++l) dl[l] = 0.f;
#pragma unroll
  for (int k = 0; k < 16; ++k) {
    float Lk = L[k];
#pragma unroll
    for (int g = 0; g < 4; ++g) {
      float4 rr = RR4[k * 4 + g];
      dl[4*g+0] += Lk * rr.x; dl[4*g+1] += Lk * rr.y;
      dl[4*g+2] += Lk * rr.z; dl[4*g+3] += Lk * rr.w;
    }
  }
#pragma unroll
  for (int a4 = 0; a4 < 16; ++a4) {
    float4 qq = q4[a4];
#pragma unroll
    for (int c = 0; c < 4; ++c) {
      float qa = (c == 0) ? qq.x : (c == 1) ? qq.y : (c == 2) ? qq.z : qq.w;
      const float4* kr = (const float4*)(M + 256 + (a4 * 4 + c) * 16);
#pragma unroll
      for (int g = 0; g < 4; ++g) {
        float4 k4 = kr[g];
        dl[4*g+0] -= qa * k4.x; dl[4*g+1] -= qa * k4.y;
        dl[4*g+2] -= qa * k4.z; dl[4*g+3] -= qa * k4.w;
      }
    }
  }
  float dot = 0.f;
#pragma unroll
  for (int l = 0; l < 16; ++l) {
    float lsl = lv[l] * ri;
    dl[l] *= lsl;
    dot += lsl * dl[l];
  }
#pragma unroll
  for (int l = 0; l < 16; ++l) {
    float lsl = lv[l] * ri;
    lv[l] -= STEPSZ * (dl[l] - lsl * dot) * ri;
  }
}

// M: MLL (256) + MLQT[a*16+k] (1024); C: C1(16), C2(16), SRN(16)
__device__ __forceinline__ void colUpdate(const float* M, const float* C,
                                          const float4* k4, float nv[16]) {
  const float4* MLL4 = (const float4*)M;
  const float* C1 = C;
  const float* C2 = C + 16;
  const float* SRN = C + 32;
  float rp2[16];
#pragma unroll
  for (int l = 0; l < 16; ++l) rp2[l] = nv[l] * nv[l];
  float s[16];
#pragma unroll
  for (int k = 0; k < 16; ++k) {
    float a0 = 0.f;
#pragma unroll
    for (int g = 0; g < 4; ++g) {
      float4 m = MLL4[k * 4 + g];
      a0 += m.x * rp2[4*g+0] + m.y * rp2[4*g+1] + m.z * rp2[4*g+2] + m.w * rp2[4*g+3];
    }
    s[k] = a0;
  }
#pragma unroll
  for (int a4 = 0; a4 < 16; ++a4) {
    float4 kk = k4[a4];
#pragma unroll
    for (int c = 0; c < 4; ++c) {
      float ka = (c == 0) ? kk.x : (c == 1) ? kk.y : (c == 2) ? kk.z : kk.w;
      const float4* mq = (const float4*)(M + 256 + (a4 * 4 + c) * 16);
#pragma unroll
      for (int g = 0; g < 4; ++g) {
        float4 m = mq[g];
        s[4*g+0] -= ka * m.x; s[4*g+1] -= ka * m.y;
        s[4*g+2] -= ka * m.z; s[4*g+3] -= ka * m.w;
      }
    }
  }
#pragma unroll
  for (int k = 0; k < 16; ++k) {
    float rs = nv[k] * SRN[k];
    float d2 = rs * s[k];
    nv[k] = C1[k] * nv[k] - C2[k] * d2;
  }
}

// ---------------------------------------------------------------------------
// kStep<MODE>: grid (32, BH_, 2), 256-row tiles.
// Matrices live at B+MAT_OFF (disjoint from stage) -> no post-update barrier.
// ---------------------------------------------------------------------------
template <int MODE>
__global__ void __launch_bounds__(256, 5) kStep(const float* __restrict__ accF,
                                                const float* __restrict__ q,
                                                const float* __restrict__ key,
                                                const float* __restrict__ vv,
                                                const float* __restrict__ lp0,
                                                const float* __restrict__ rp0,
                                                float* __restrict__ lp,
                                                float* __restrict__ rp,
                                                float* __restrict__ part,
                                                float* __restrict__ part2) {
  const int bh = blockIdx.y, bx = blockIdx.x, t = threadIdx.x;
  const int j0 = bx * 256, j = j0 + t;
  const int bb = bh * 32 + bx;
  __shared__ float B[B_FLOATS];
  const float* A = accF + (size_t)bh * ACCF_STRIDE;
  const float* qb = q + (size_t)bh * S_ * D_;
  const float* kb = key + (size_t)bh * S_ * D_;
  const size_t base = ((size_t)bh * S_ + j) * 16;

  if (blockIdx.z == 0) {
    float lv[16];
    const float4* s4 = (const float4*)((MODE == 0 ? lp0 : lp) + base);
    float4 a0 = s4[0], a1 = s4[1], a2 = s4[2], a3 = s4[3];
    lv[0]=a0.x; lv[1]=a0.y; lv[2]=a0.z; lv[3]=a0.w;
    lv[4]=a1.x; lv[5]=a1.y; lv[6]=a1.z; lv[7]=a1.w;
    lv[8]=a2.x; lv[9]=a2.y; lv[10]=a2.z; lv[11]=a2.w;
    lv[12]=a3.x; lv[13]=a3.y; lv[14]=a3.z; lv[15]=a3.w;
    if (MODE >= 1) {
      for (int e = t; e < 1280; e += 256) B[MAT_OFF + e] = A[1280 + e];  // RRS + KRT
      __syncthreads();
      rowUpdate(B + MAT_OFF, (const float4*)(qb + (size_t)j * D_), lv);
      // no barrier: stage region (B[0..5119]) is disjoint from matrices
    }
    {
      float4* d4 = (float4*)(lp + base);
      d4[0] = make_float4(lv[0], lv[1], lv[2], lv[3]);
      d4[1] = make_float4(lv[4], lv[5], lv[6], lv[7]);
      d4[2] = make_float4(lv[8], lv[9], lv[10], lv[11]);
      d4[3] = make_float4(lv[12], lv[13], lv[14], lv[15]);
    }
    if (MODE == 2) return;
    float L[16];
    {
      float m2 = 0.f;
#pragma unroll
      for (int l = 0; l < 16; ++l) m2 += lv[l] * lv[l];
      float r2 = 1.0f / m2;
#pragma unroll
      for (int l = 0; l < 16; ++l) L[l] = lv[l] * lv[l] * r2;
    }
    reduceSide<0>(qb, j0, t, L, B, part + (size_t)bb * PART_STRIDE);
  } else {
    float nv[16];
    if (MODE == 0) {
      const float* rsrc = rp0 + (size_t)bh * 16 * S_ + j;   // original [r][S]
#pragma unroll
      for (int k = 0; k < 16; ++k) nv[k] = rsrc[(size_t)k * S_];
    } else {
      const float4* r4 = (const float4*)(rp + base);        // internal [i][16]
      float4 a0 = r4[0], a1 = r4[1], a2 = r4[2], a3 = r4[3];
      nv[0]=a0.x; nv[1]=a0.y; nv[2]=a0.z; nv[3]=a0.w;
      nv[4]=a1.x; nv[5]=a1.y; nv[6]=a1.z; nv[7]=a1.w;
      nv[8]=a2.x; nv[9]=a2.y; nv[10]=a2.z; nv[11]=a2.w;
      nv[12]=a3.x; nv[13]=a3.y; nv[14]=a3.z; nv[15]=a3.w;
      for (int e = t; e < 1328; e += 256)
        B[MAT_OFF + e] = (e < 1280) ? A[e] : A[1280 + e];
      __syncthreads();
      colUpdate(B + MAT_OFF, B + MAT_OFF + 1280,
                (const float4*)(kb + (size_t)j * D_), nv);
      // no barrier needed before stage (disjoint regions)
    }
    {
      float4* d4 = (float4*)(rp + base);
      d4[0] = make_float4(nv[0], nv[1], nv[2], nv[3]);
      d4[1] = make_float4(nv[4], nv[5], nv[6], nv[7]);
      d4[2] = make_float4(nv[8], nv[9], nv[10], nv[11]);
      d4[3] = make_float4(nv[12], nv[13], nv[14], nv[15]);
    }
    float rp2[16];
#pragma unroll
    for (int l = 0; l < 16; ++l) rp2[l] = nv[l] * nv[l];
    if (MODE < 2)
      reduceSide<1>(kb, j0, t, rp2, B, part + (size_t)bb * PART_STRIDE + 1280);
    else
      reduceSide<2>(vv + (size_t)bh * S_ * D_, j0, t, rp2, B,
                    part2 + (size_t)bb * PART2_STRIDE);
  }
}

// ---------------------------------------------------------------------------
// kB: one block per bh. Sum 32 partials -> derived matrices + analytic PJ, c1/c2.
// ---------------------------------------------------------------------------
__global__ void __launch_bounds__(256) kB(const float* __restrict__ part,
                                          float* __restrict__ accF) {
  const int bh = blockIdx.x, t = threadIdx.x;
  __shared__ float raw[PART_STRIDE];
  __shared__ float inn[16], srn[16];
  const float* p0 = part + (size_t)bh * 32 * PART_STRIDE;
  for (int vI = t; vI < PART_STRIDE; vI += 256) {
    float s = 0.f;
    const float* p = p0 + vI;
#pragma unroll 8
    for (int b2 = 0; b2 < 32; ++b2) s += p[(size_t)b2 * PART_STRIDE];
    raw[vI] = s;
  }
  __syncthreads();
  if (t < 16) {
    float N = raw[2560 + t];
    inn[t] = 1.0f / N;
    srn[t] = rsqrtf(N);
  }
  __syncthreads();
  float* o = accF + (size_t)bh * ACCF_STRIDE;
  o[t] = raw[1024 + t] * CC * inn[t & 15];                        // MLL[k][l]
  o[1280 + t] = raw[2304 + t] * CC * inn[t >> 4] * inn[t & 15];   // RRS[k][l]
#pragma unroll
  for (int r = 0; r < 4; ++r) {
    int e = t + r * 256;
    o[256 + e] = raw[e] * CC;                                     // MLQT[a*16+k]
  }
#pragma unroll
  for (int r = 0; r < 4; ++r) {
    int e = t + r * 256;
    o[1536 + e] = raw[1280 + e] * CC * inn[e & 15];               // KRT[a*16+l]
  }
  if (t < 16) {
    int k = t;
    float s = 0.f;
#pragma unroll
    for (int l = 0; l < 16; ++l)
      s += raw[1024 + k * 16 + l] * CC * inn[l] * raw[2304 + k * 16 + l];
#pragma unroll
    for (int a = 0; a < 64; ++a)
      s -= raw[a * 16 + k] * CC * raw[1280 + a * 16 + k];
    float PJ = inn[k] * s;
    o[2560 + t] = 1.0f + STEPSZ * PJ * inn[t];
    o[2576 + t] = STEPSZ * srn[t];
    o[2592 + t] = srn[t];
  }
}

__global__ void __launch_bounds__(256) kBF(const float* __restrict__ part2,
                                           float* __restrict__ RVs) {
  const int bh = blockIdx.x, t = threadIdx.x;
  __shared__ float raw[PART2_STRIDE];
  __shared__ float inn[16];
  const float* p0 = part2 + (size_t)bh * 32 * PART2_STRIDE;
  for (int vI = t; vI < PART2_STRIDE; vI += 256) {
    float s = 0.f;
    const float* p = p0 + vI;
#pragma unroll 8
    for (int b2 = 0; b2 < 32; ++b2) s += p[(size_t)b2 * PART2_STRIDE];
    raw[vI] = s;
  }
  __syncthreads();
  if (t < 16) inn[t] = 1.0f / raw[1024 + t];
  __syncthreads();
#pragma unroll
  for (int r = 0; r < 4; ++r) {
    int e = t + r * 256;  // e = k*64+d ; RV raw at [d*16+k]
    RVs[(size_t)bh * 1024 + e] = raw[((e & 63) << 4) + (e >> 6)] * inn[e >> 6];
  }
}

// out[j][d] = sum_k unit(lp_j)^2[k] * RVs[bh][k][d]
__global__ void __launch_bounds__(256) kOut(const float* __restrict__ lp,
                                            const float* __restrict__ RVs,
                                            float* __restrict__ out) {
  const int bh = blockIdx.y, t = threadIdx.x;
  __shared__ float rvs[1024];
#pragma unroll
  for (int r = 0; r < 4; ++r) rvs[t + r * 256] = RVs[(size_t)bh * 1024 + t + r * 256];
  __syncthreads();
  const int j = blockIdx.x * 256 + t;
  size_t base = ((size_t)bh * S_ + j) * 16;
  const float4* lp4 = (const float4*)(lp + base);
  float4 a0 = lp4[0], a1 = lp4[1], a2 = lp4[2], a3 = lp4[3];
  float lv[16] = {a0.x,a0.y,a0.z,a0.w, a1.x,a1.y,a1.z,a1.w,
                  a2.x,a2.y,a2.z,a2.w, a3.x,a3.y,a3.z,a3.w};
  float n2 = 0.f;
#pragma unroll
  for (int l = 0; l < 16; ++l) n2 += lv[l] * lv[l];
  float r2 = 1.0f / n2;
  float L[16];
#pragma unroll
  for (int l = 0; l < 16; ++l) L[l] = lv[l] * lv[l] * r2;
  float o[64];
#pragma unroll
  for (int d = 0; d < 64; ++d) o[d] = 0.f;
  const float4* rv4 = (const float4*)rvs;
#pragma unroll
  for (int k = 0; k < 16; ++k) {
    float Lk = L[k];
#pragma unroll
    for (int d4 = 0; d4 < 16; ++d4) {
      float4 r = rv4[k * 16 + d4];
      o[4*d4+0] += Lk * r.x; o[4*d4+1] += Lk * r.y;
      o[4*d4+2] += Lk * r.z; o[4*d4+3] += Lk * r.w;
    }
  }
  float4* o4 = (float4*)(out + ((size_t)bh * S_ + j) * D_);
#pragma unroll
  for (int d4 = 0; d4 < 16; ++d4)
    o4[d4] = make_float4(o[4*d4+0], o[4*d4+1], o[4*d4+2], o[4*d4+3]);
}

extern "C" void kernel_launch(void* const* d_in, const int* in_sizes, int n_in,
                              void* d_out, int out_size, void* d_ws, size_t ws_size,
                              hipStream_t stream) {
  (void)in_sizes; (void)n_in; (void)out_size; (void)ws_size;
  const float* q = (const float*)d_in[0];
  const float* key = (const float*)d_in[1];
  const float* v = (const float*)d_in[2];
  const float* lp0 = (const float*)d_in[3];
  const float* rp0 = (const float*)d_in[4];
  float* out = (float*)d_out;
  float* ws = (float*)d_ws;

  float* lp = ws;                  // 3,145,728 floats ([j][16])
  float* rp = lp + LP_N;           // 3,145,728 ([i][16] internal)
  float* part = rp + LP_N;         // 1,978,368
  float* accF = part + PART_N;     // 62,976
  float* part2 = accF + ACCF_N;    // 798,720
  float* RVs = part2 + PART2_N;    // 24,576
  // total 9,156,096 floats = 36.6 MB

  dim3 blk(256);
  dim3 gS(32, BH_, 2);
  kStep<0><<<gS, blk, 0, stream>>>(accF, q, key, v, lp0, rp0, lp, rp, part, part2);
  for (int s = 0; s < 10; ++s) {
    kB<<<dim3(BH_), blk, 0, stream>>>(part, accF);
    if (s < 9)
      kStep<1><<<gS, blk, 0, stream>>>(accF, q, key, v, lp0, rp0, lp, rp, part, part2);
    else
      kStep<2><<<gS, blk, 0, stream>>>(accF, q, key, v, lp0, rp0, lp, rp, part, part2);
  }
  kBF<<<dim3(BH_), blk, 0, stream>>>(part2, RVs);
  kOut<<<dim3(32, BH_), blk, 0, stream>>>(lp, RVs, out);
}

// Round 13
// 877.199 us; speedup vs baseline: 1.1374x; 1.1374x over previous
//
#include <hip/hip_runtime.h>

// LowRankAttention: B=2,H=12 (BH=24), S=8192, D=64, RANK=16, 10 steps, fp32.
// R11 structure (proven 840us); phase-2 unroll 2 to nudge VGPR <=102 naturally.
#define S_ 8192
#define D_ 64
#define BH_ 24

static constexpr float INV_S2 = 1.0f / (8192.0f * 8192.0f);
static constexpr float STEPSZ = 1000.0f;
static constexpr float CC = 2.0f * INV_S2;

#define LP_N (BH_ * S_ * 16)
#define PART_STRIDE 2576   // L: LQ[a*16+l] 0..1023, LL[l*16+c] 1024..1279; R-side +1280; N 2560
#define PART_N (BH_ * 32 * PART_STRIDE)
#define ACCF_STRIDE 2624   // MLL 0, MLQT[a*16+k] 256, RRS 1280, KRT[a*16+l] 1536, C1 2560, C2 2576, SRN 2592
#define ACCF_N (BH_ * ACCF_STRIDE)
#define PART2_STRIDE 1040  // RV[d*16+l] 0..1023, N 1024
#define PART2_N (BH_ * 32 * PART2_STRIDE)

// ---------------------------------------------------------------------------
// Low-VGPR block reduction over 256 rows. KIND 0: LQ+LL; 1: KR+RR+N; 2: RV+N.
// Phase 1 (mini): tc-scheme LL/RR + N (aX[16]+aN[16]), results to RDs (disjoint).
// Phase 2 (main): lane owns column pair a=2*(t&31); rows (t>>5)+8*it; aQ0/aQ1
//   (32 regs). Vv reads are half-wave broadcasts; q read = coalesced float2.
//   One shfl_xor(32) combines the wave's two row-slots. unroll 2 (VGPR trim).
// B[6400]: ST = B[0..5119] (stage 256x20); RDs = B[5120..6271]; aQ dump
// overlays ST after the post-main barrier.
// ---------------------------------------------------------------------------
template <int KIND>
__device__ __forceinline__ void reduceSide(const float* __restrict__ sb, int jbase, int t,
                                           const float* vals, float* B,
                                           float* __restrict__ pbase) {
  const int lane = t & 63, w = t >> 6;
  float* ST = B;
  float* RDs = B + 5120;           // 4 waves x 288 = 1152
  {
    float4* st = (float4*)(ST + t * 20);
    st[0] = make_float4(vals[0], vals[1], vals[2], vals[3]);
    st[1] = make_float4(vals[4], vals[5], vals[6], vals[7]);
    st[2] = make_float4(vals[8], vals[9], vals[10], vals[11]);
    st[3] = make_float4(vals[12], vals[13], vals[14], vals[15]);
  }
  __syncthreads();

  // ---- phase 1: mini loop (aX = LL/RR column tcx; aN = row sums) ----
  {
    const int tcx = t & 15;
    float aX[16], aN[16];
#pragma unroll
    for (int l = 0; l < 16; ++l) { aX[l] = 0.f; aN[l] = 0.f; }
#pragma unroll 4
    for (int it = 0; it < 16; ++it) {
      const int jl = (t >> 4) + (it << 4);   // slot16 + 16*it
      const float4* Vw = (const float4*)(ST + jl * 20);
      float4 b0 = Vw[0], b1 = Vw[1], b2 = Vw[2], b3 = Vw[3];
      float Vv[16] = {b0.x,b0.y,b0.z,b0.w, b1.x,b1.y,b1.z,b1.w,
                      b2.x,b2.y,b2.z,b2.w, b3.x,b3.y,b3.z,b3.w};
      float xc = (KIND < 2) ? ST[jl * 20 + tcx] : 0.f;
#pragma unroll
      for (int l = 0; l < 16; ++l) {
        if (KIND < 2) aX[l] += Vv[l] * xc;
        if (KIND >= 1) aN[l] += Vv[l];
      }
    }
#pragma unroll
    for (int l = 0; l < 16; ++l) {
      if (KIND < 2) { float v = aX[l]; v += __shfl_xor(v, 16); v += __shfl_xor(v, 32); aX[l] = v; }
      if (KIND >= 1) { float v = aN[l]; v += __shfl_xor(v, 16); v += __shfl_xor(v, 32); aN[l] = v; }
    }
    if (KIND < 2 && lane < 16) {
      float* p = RDs + w * 288 + lane * 17;
#pragma unroll
      for (int l = 0; l < 16; ++l) p[l] = aX[l];
    }
    if (KIND >= 1 && lane == 0) {
      float* p = RDs + w * 288 + 272;
#pragma unroll
      for (int l = 0; l < 16; ++l) p[l] = aN[l];
    }
  }

  // ---- phase 2: main pair loop (unroll 2 to trim in-flight registers) ----
  float aQ0[16], aQ1[16];
#pragma unroll
  for (int l = 0; l < 16; ++l) { aQ0[l] = 0.f; aQ1[l] = 0.f; }
  {
    const int p2 = t & 31, slot8 = t >> 5;
    const float* srow = sb + (size_t)jbase * D_ + (p2 << 1);
#pragma unroll 2
    for (int it = 0; it < 32; ++it) {
      const int jl = slot8 + (it << 3);
      const float4* Vw = (const float4*)(ST + jl * 20);
      float4 b0 = Vw[0], b1 = Vw[1], b2 = Vw[2], b3 = Vw[3];
      float2 qq = *(const float2*)(srow + (size_t)jl * D_);
      aQ0[0]  += qq.x * b0.x; aQ1[0]  += qq.y * b0.x;
      aQ0[1]  += qq.x * b0.y; aQ1[1]  += qq.y * b0.y;
      aQ0[2]  += qq.x * b0.z; aQ1[2]  += qq.y * b0.z;
      aQ0[3]  += qq.x * b0.w; aQ1[3]  += qq.y * b0.w;
      aQ0[4]  += qq.x * b1.x; aQ1[4]  += qq.y * b1.x;
      aQ0[5]  += qq.x * b1.y; aQ1[5]  += qq.y * b1.y;
      aQ0[6]  += qq.x * b1.z; aQ1[6]  += qq.y * b1.z;
      aQ0[7]  += qq.x * b1.w; aQ1[7]  += qq.y * b1.w;
      aQ0[8]  += qq.x * b2.x; aQ1[8]  += qq.y * b2.x;
      aQ0[9]  += qq.x * b2.y; aQ1[9]  += qq.y * b2.y;
      aQ0[10] += qq.x * b2.z; aQ1[10] += qq.y * b2.z;
      aQ0[11] += qq.x * b2.w; aQ1[11] += qq.y * b2.w;
      aQ0[12] += qq.x * b3.x; aQ1[12] += qq.y * b3.x;
      aQ0[13] += qq.x * b3.y; aQ1[13] += qq.y * b3.y;
      aQ0[14] += qq.x * b3.z; aQ1[14] += qq.y * b3.z;
      aQ0[15] += qq.x * b3.w; aQ1[15] += qq.y * b3.w;
    }
  }
#pragma unroll
  for (int l = 0; l < 16; ++l) {
    aQ0[l] += __shfl_xor(aQ0[l], 32);
    aQ1[l] += __shfl_xor(aQ1[l], 32);
  }
  __syncthreads();   // all ST reads done; overlay aQ dump
  if (lane < 32) {
    float* g = B + w * 1056 + lane * 33;
#pragma unroll
    for (int l = 0; l < 16; ++l) { g[l] = aQ0[l]; g[16 + l] = aQ1[l]; }
  }
  __syncthreads();
  // gather LQ: pbase[a*16+l], a = 2*p + c
#pragma unroll
  for (int r = 0; r < 4; ++r) {
    int o = t + r * 256;
    int a = o >> 4, l = o & 15;
    int idx = (a >> 1) * 33 + ((a & 1) << 4) + l;
    pbase[a * 16 + l] = B[idx] + B[1056 + idx] + B[2112 + idx] + B[3168 + idx];
  }
  if (KIND < 2) {
    int c = t >> 4, l = t & 15;
    int idx = 5120 + c * 17 + l;
    pbase[1024 + l * 16 + c] = B[idx] + B[288 + idx] + B[576 + idx] + B[864 + idx];
  }
  if (KIND >= 1 && t < 16) {
    int idx = 5120 + 272 + t;
    pbase[(KIND == 1 ? 1280 : 1024) + t] =
        B[idx] + B[288 + idx] + B[576 + idx] + B[864 + idx];
  }
  // no trailing barrier: reduceSide is the last block-wide LDS use per kernel
}

// M: RRS[k][l] (256) + KRT[a*16+l] (1024); ls[] recomputed inline
__device__ __forceinline__ void rowUpdate(const float* M, const float4* q4, float lv[16]) {
  const float4* RR4 = (const float4*)M;
  float n2 = 0.f;
#pragma unroll
  for (int l = 0; l < 16; ++l) n2 += lv[l] * lv[l];
  float ri = rsqrtf(n2);
  float r2 = ri * ri;
  float L[16];
#pragma unroll
  for (int l = 0; l < 16; ++l) L[l] = lv[l] * lv[l] * r2;
  float dl[16];
#pragma unroll
  for (int l = 0; l < 16; ++l) dl[l] = 0.f;
#pragma unroll
  for (int k = 0; k < 16; ++k) {
    float Lk = L[k];
#pragma unroll
    for (int g = 0; g < 4; ++g) {
      float4 rr = RR4[k * 4 + g];
      dl[4*g+0] += Lk * rr.x; dl[4*g+1] += Lk * rr.y;
      dl[4*g+2] += Lk * rr.z; dl[4*g+3] += Lk * rr.w;
    }
  }
#pragma unroll
  for (int a4 = 0; a4 < 16; ++a4) {
    float4 qq = q4[a4];
#pragma unroll
    for (int c = 0; c < 4; ++c) {
      float qa = (c == 0) ? qq.x : (c == 1) ? qq.y : (c == 2) ? qq.z : qq.w;
      const float4* kr = (const float4*)(M + 256 + (a4 * 4 + c) * 16);
#pragma unroll
      for (int g = 0; g < 4; ++g) {
        float4 k4 = kr[g];
        dl[4*g+0] -= qa * k4.x; dl[4*g+1] -= qa * k4.y;
        dl[4*g+2] -= qa * k4.z; dl[4*g+3] -= qa * k4.w;
      }
    }
  }
  float dot = 0.f;
#pragma unroll
  for (int l = 0; l < 16; ++l) {
    float lsl = lv[l] * ri;
    dl[l] *= lsl;
    dot += lsl * dl[l];
  }
#pragma unroll
  for (int l = 0; l < 16; ++l) {
    float lsl = lv[l] * ri;
    lv[l] -= STEPSZ * (dl[l] - lsl * dot) * ri;
  }
}

// M: MLL (256) + MLQT[a*16+k] (1024); C: C1(16), C2(16), SRN(16)
__device__ __forceinline__ void colUpdate(const float* M, const float* C,
                                          const float4* k4, float nv[16]) {
  const float4* MLL4 = (const float4*)M;
  const float* C1 = C;
  const float* C2 = C + 16;
  const float* SRN = C + 32;
  float rp2[16];
#pragma unroll
  for (int l = 0; l < 16; ++l) rp2[l] = nv[l] * nv[l];
  float s[16];
#pragma unroll
  for (int k = 0; k < 16; ++k) {
    float a0 = 0.f;
#pragma unroll
    for (int g = 0; g < 4; ++g) {
      float4 m = MLL4[k * 4 + g];
      a0 += m.x * rp2[4*g+0] + m.y * rp2[4*g+1] + m.z * rp2[4*g+2] + m.w * rp2[4*g+3];
    }
    s[k] = a0;
  }
#pragma unroll
  for (int a4 = 0; a4 < 16; ++a4) {
    float4 kk = k4[a4];
#pragma unroll
    for (int c = 0; c < 4; ++c) {
      float ka = (c == 0) ? kk.x : (c == 1) ? kk.y : (c == 2) ? kk.z : kk.w;
      const float4* mq = (const float4*)(M + 256 + (a4 * 4 + c) * 16);
#pragma unroll
      for (int g = 0; g < 4; ++g) {
        float4 m = mq[g];
        s[4*g+0] -= ka * m.x; s[4*g+1] -= ka * m.y;
        s[4*g+2] -= ka * m.z; s[4*g+3] -= ka * m.w;
      }
    }
  }
#pragma unroll
  for (int k = 0; k < 16; ++k) {
    float rs = nv[k] * SRN[k];
    float d2 = rs * s[k];
    nv[k] = C1[k] * nv[k] - C2[k] * d2;
  }
}

// ---------------------------------------------------------------------------
// kStep<MODE>: grid (32, BH_, 2), 256-row tiles (R11 shell, no forced bounds).
// z=0 row side (lp, q); z=1 col side (rp, key / v when MODE==2).
// ---------------------------------------------------------------------------
template <int MODE>
__global__ void __launch_bounds__(256) kStep(const float* __restrict__ accF,
                                             const float* __restrict__ q,
                                             const float* __restrict__ key,
                                             const float* __restrict__ vv,
                                             const float* __restrict__ lp0,
                                             const float* __restrict__ rp0,
                                             float* __restrict__ lp,
                                             float* __restrict__ rp,
                                             float* __restrict__ part,
                                             float* __restrict__ part2) {
  const int bh = blockIdx.y, bx = blockIdx.x, t = threadIdx.x;
  const int j0 = bx * 256, j = j0 + t;
  const int bb = bh * 32 + bx;
  __shared__ float B[6400];
  const float* A = accF + (size_t)bh * ACCF_STRIDE;
  const float* qb = q + (size_t)bh * S_ * D_;
  const float* kb = key + (size_t)bh * S_ * D_;
  const size_t base = ((size_t)bh * S_ + j) * 16;

  if (blockIdx.z == 0) {
    float lv[16];
    const float4* s4 = (const float4*)((MODE == 0 ? lp0 : lp) + base);
    float4 a0 = s4[0], a1 = s4[1], a2 = s4[2], a3 = s4[3];
    lv[0]=a0.x; lv[1]=a0.y; lv[2]=a0.z; lv[3]=a0.w;
    lv[4]=a1.x; lv[5]=a1.y; lv[6]=a1.z; lv[7]=a1.w;
    lv[8]=a2.x; lv[9]=a2.y; lv[10]=a2.z; lv[11]=a2.w;
    lv[12]=a3.x; lv[13]=a3.y; lv[14]=a3.z; lv[15]=a3.w;
    if (MODE >= 1) {
      for (int e = t; e < 1280; e += 256) B[e] = A[1280 + e];  // RRS + KRT
      __syncthreads();
      rowUpdate(B, (const float4*)(qb + (size_t)j * D_), lv);
      __syncthreads();  // matrices consumed before stage overwrites B
    }
    {
      float4* d4 = (float4*)(lp + base);
      d4[0] = make_float4(lv[0], lv[1], lv[2], lv[3]);
      d4[1] = make_float4(lv[4], lv[5], lv[6], lv[7]);
      d4[2] = make_float4(lv[8], lv[9], lv[10], lv[11]);
      d4[3] = make_float4(lv[12], lv[13], lv[14], lv[15]);
    }
    if (MODE == 2) return;
    float L[16];
    {
      float m2 = 0.f;
#pragma unroll
      for (int l = 0; l < 16; ++l) m2 += lv[l] * lv[l];
      float r2 = 1.0f / m2;
#pragma unroll
      for (int l = 0; l < 16; ++l) L[l] = lv[l] * lv[l] * r2;
    }
    reduceSide<0>(qb, j0, t, L, B, part + (size_t)bb * PART_STRIDE);
  } else {
    float nv[16];
    if (MODE == 0) {
      const float* rsrc = rp0 + (size_t)bh * 16 * S_ + j;   // original [r][S]
#pragma unroll
      for (int k = 0; k < 16; ++k) nv[k] = rsrc[(size_t)k * S_];
    } else {
      const float4* r4 = (const float4*)(rp + base);        // internal [i][16]
      float4 a0 = r4[0], a1 = r4[1], a2 = r4[2], a3 = r4[3];
      nv[0]=a0.x; nv[1]=a0.y; nv[2]=a0.z; nv[3]=a0.w;
      nv[4]=a1.x; nv[5]=a1.y; nv[6]=a1.z; nv[7]=a1.w;
      nv[8]=a2.x; nv[9]=a2.y; nv[10]=a2.z; nv[11]=a2.w;
      nv[12]=a3.x; nv[13]=a3.y; nv[14]=a3.z; nv[15]=a3.w;
      for (int e = t; e < 1328; e += 256) B[e] = (e < 1280) ? A[e] : A[1280 + e];
      __syncthreads();
      colUpdate(B, B + 1280, (const float4*)(kb + (size_t)j * D_), nv);
      __syncthreads();  // matrices consumed
    }
    {
      float4* d4 = (float4*)(rp + base);
      d4[0] = make_float4(nv[0], nv[1], nv[2], nv[3]);
      d4[1] = make_float4(nv[4], nv[5], nv[6], nv[7]);
      d4[2] = make_float4(nv[8], nv[9], nv[10], nv[11]);
      d4[3] = make_float4(nv[12], nv[13], nv[14], nv[15]);
    }
    float rp2[16];
#pragma unroll
    for (int l = 0; l < 16; ++l) rp2[l] = nv[l] * nv[l];
    if (MODE < 2)
      reduceSide<1>(kb, j0, t, rp2, B, part + (size_t)bb * PART_STRIDE + 1280);
    else
      reduceSide<2>(vv + (size_t)bh * S_ * D_, j0, t, rp2, B,
                    part2 + (size_t)bb * PART2_STRIDE);
  }
}

// ---------------------------------------------------------------------------
// kB: one block per bh. Sum 32 partials -> derived matrices + analytic PJ, c1/c2.
// ---------------------------------------------------------------------------
__global__ void __launch_bounds__(256) kB(const float* __restrict__ part,
                                          float* __restrict__ accF) {
  const int bh = blockIdx.x, t = threadIdx.x;
  __shared__ float raw[PART_STRIDE];
  __shared__ float inn[16], srn[16];
  const float* p0 = part + (size_t)bh * 32 * PART_STRIDE;
  for (int vI = t; vI < PART_STRIDE; vI += 256) {
    float s = 0.f;
    const float* p = p0 + vI;
#pragma unroll 8
    for (int b2 = 0; b2 < 32; ++b2) s += p[(size_t)b2 * PART_STRIDE];
    raw[vI] = s;
  }
  __syncthreads();
  if (t < 16) {
    float N = raw[2560 + t];
    inn[t] = 1.0f / N;
    srn[t] = rsqrtf(N);
  }
  __syncthreads();
  float* o = accF + (size_t)bh * ACCF_STRIDE;
  o[t] = raw[1024 + t] * CC * inn[t & 15];                        // MLL[k][l]
  o[1280 + t] = raw[2304 + t] * CC * inn[t >> 4] * inn[t & 15];   // RRS[k][l]
#pragma unroll
  for (int r = 0; r < 4; ++r) {
    int e = t + r * 256;
    o[256 + e] = raw[e] * CC;                                     // MLQT[a*16+k]
  }
#pragma unroll
  for (int r = 0; r < 4; ++r) {
    int e = t + r * 256;
    o[1536 + e] = raw[1280 + e] * CC * inn[e & 15];               // KRT[a*16+l]
  }
  if (t < 16) {
    int k = t;
    float s = 0.f;
#pragma unroll
    for (int l = 0; l < 16; ++l)
      s += raw[1024 + k * 16 + l] * CC * inn[l] * raw[2304 + k * 16 + l];
#pragma unroll
    for (int a = 0; a < 64; ++a)
      s -= raw[a * 16 + k] * CC * raw[1280 + a * 16 + k];
    float PJ = inn[k] * s;
    o[2560 + t] = 1.0f + STEPSZ * PJ * inn[t];
    o[2576 + t] = STEPSZ * srn[t];
    o[2592 + t] = srn[t];
  }
}

__global__ void __launch_bounds__(256) kBF(const float* __restrict__ part2,
                                           float* __restrict__ RVs) {
  const int bh = blockIdx.x, t = threadIdx.x;
  __shared__ float raw[PART2_STRIDE];
  __shared__ float inn[16];
  const float* p0 = part2 + (size_t)bh * 32 * PART2_STRIDE;
  for (int vI = t; vI < PART2_STRIDE; vI += 256) {
    float s = 0.f;
    const float* p = p0 + vI;
#pragma unroll 8
    for (int b2 = 0; b2 < 32; ++b2) s += p[(size_t)b2 * PART2_STRIDE];
    raw[vI] = s;
  }
  __syncthreads();
  if (t < 16) inn[t] = 1.0f / raw[1024 + t];
  __syncthreads();
#pragma unroll
  for (int r = 0; r < 4; ++r) {
    int e = t + r * 256;  // e = k*64+d ; RV raw at [d*16+k]
    RVs[(size_t)bh * 1024 + e] = raw[((e & 63) << 4) + (e >> 6)] * inn[e >> 6];
  }
}

// out[j][d] = sum_k unit(lp_j)^2[k] * RVs[bh][k][d]
__global__ void __launch_bounds__(256) kOut(const float* __restrict__ lp,
                                            const float* __restrict__ RVs,
                                            float* __restrict__ out) {
  const int bh = blockIdx.y, t = threadIdx.x;
  __shared__ float rvs[1024];
#pragma unroll
  for (int r = 0; r < 4; ++r) rvs[t + r * 256] = RVs[(size_t)bh * 1024 + t + r * 256];
  __syncthreads();
  const int j = blockIdx.x * 256 + t;
  size_t base = ((size_t)bh * S_ + j) * 16;
  const float4* lp4 = (const float4*)(lp + base);
  float4 a0 = lp4[0], a1 = lp4[1], a2 = lp4[2], a3 = lp4[3];
  float lv[16] = {a0.x,a0.y,a0.z,a0.w, a1.x,a1.y,a1.z,a1.w,
                  a2.x,a2.y,a2.z,a2.w, a3.x,a3.y,a3.z,a3.w};
  float n2 = 0.f;
#pragma unroll
  for (int l = 0; l < 16; ++l) n2 += lv[l] * lv[l];
  float r2 = 1.0f / n2;
  float L[16];
#pragma unroll
  for (int l = 0; l < 16; ++l) L[l] = lv[l] * lv[l] * r2;
  float o[64];
#pragma unroll
  for (int d = 0; d < 64; ++d) o[d] = 0.f;
  const float4* rv4 = (const float4*)rvs;
#pragma unroll
  for (int k = 0; k < 16; ++k) {
    float Lk = L[k];
#pragma unroll
    for (int d4 = 0; d4 < 16; ++d4) {
      float4 r = rv4[k * 16 + d4];
      o[4*d4+0] += Lk * r.x; o[4*d4+1] += Lk * r.y;
      o[4*d4+2] += Lk * r.z; o[4*d4+3] += Lk * r.w;
    }
  }
  float4* o4 = (float4*)(out + ((size_t)bh * S_ + j) * D_);
#pragma unroll
  for (int d4 = 0; d4 < 16; ++d4)
    o4[d4] = make_float4(o[4*d4+0], o[4*d4+1], o[4*d4+2], o[4*d4+3]);
}

extern "C" void kernel_launch(void* const* d_in, const int* in_sizes, int n_in,
                              void* d_out, int out_size, void* d_ws, size_t ws_size,
                              hipStream_t stream) {
  (void)in_sizes; (void)n_in; (void)out_size; (void)ws_size;
  const float* q = (const float*)d_in[0];
  const float* key = (const float*)d_in[1];
  const float* v = (const float*)d_in[2];
  const float* lp0 = (const float*)d_in[3];
  const float* rp0 = (const float*)d_in[4];
  float* out = (float*)d_out;
  float* ws = (float*)d_ws;

  float* lp = ws;                  // 3,145,728 floats ([j][16])
  float* rp = lp + LP_N;           // 3,145,728 ([i][16] internal)
  float* part = rp + LP_N;         // 1,978,368
  float* accF = part + PART_N;     // 62,976
  float* part2 = accF + ACCF_N;    // 798,720
  float* RVs = part2 + PART2_N;    // 24,576
  // total 9,156,096 floats = 36.6 MB

  dim3 blk(256);
  dim3 gS(32, BH_, 2);
  kStep<0><<<gS, blk, 0, stream>>>(accF, q, key, v, lp0, rp0, lp, rp, part, part2);
  for (int s = 0; s < 10; ++s) {
    kB<<<dim3(BH_), blk, 0, stream>>>(part, accF);
    if (s < 9)
      kStep<1><<<gS, blk, 0, stream>>>(accF, q, key, v, lp0, rp0, lp, rp, part, part2);
    else
      kStep<2><<<gS, blk, 0, stream>>>(accF, q, key, v, lp0, rp0, lp, rp, part, part2);
  }
  kBF<<<dim3(BH_), blk, 0, stream>>>(part2, RVs);
  kOut<<<dim3(32, BH_), blk, 0, stream>>>(lp, RVs, out);
}

// Round 14
// 825.817 us; speedup vs baseline: 1.2081x; 1.0622x over previous
//
#include <hip/hip_runtime.h>

// LowRankAttention: B=2,H=12 (BH=24), S=8192, D=64, RANK=16, 10 steps, fp32.
// R11 structure; KIND=1 mini-phase split into two scoped passes (VGPR trim).
#define S_ 8192
#define D_ 64
#define BH_ 24

static constexpr float INV_S2 = 1.0f / (8192.0f * 8192.0f);
static constexpr float STEPSZ = 1000.0f;
static constexpr float CC = 2.0f * INV_S2;

#define LP_N (BH_ * S_ * 16)
#define PART_STRIDE 2576   // L: LQ[a*16+l] 0..1023, LL[l*16+c] 1024..1279; R-side +1280; N 2560
#define PART_N (BH_ * 32 * PART_STRIDE)
#define ACCF_STRIDE 2624   // MLL 0, MLQT[a*16+k] 256, RRS 1280, KRT[a*16+l] 1536, C1 2560, C2 2576, SRN 2592
#define ACCF_N (BH_ * ACCF_STRIDE)
#define PART2_STRIDE 1040  // RV[d*16+l] 0..1023, N 1024
#define PART2_N (BH_ * 32 * PART2_STRIDE)

// ---------------------------------------------------------------------------
// Low-VGPR block reduction over 256 rows. KIND 0: LQ+LL; 1: KR+RR+N; 2: RV+N.
// Phase 1 (mini): scoped SEPARATE passes — aX pass (KIND<2), then aN pass
//   (KIND>=1) — so peak accumulator liveness is 16, not 32.
// Phase 2 (main): lane owns column pair a=2*(t&31); aQ0/aQ1 (32 regs);
//   one shfl_xor(32); dump overlays ST after the post-main barrier.
// B[6400]: ST = B[0..5119] (stage 256x20); RDs = B[5120..6271].
// ---------------------------------------------------------------------------
template <int KIND>
__device__ __forceinline__ void reduceSide(const float* __restrict__ sb, int jbase, int t,
                                           const float* vals, float* B,
                                           float* __restrict__ pbase) {
  const int lane = t & 63, w = t >> 6;
  float* ST = B;
  float* RDs = B + 5120;           // 4 waves x 288 = 1152
  {
    float4* st = (float4*)(ST + t * 20);
    st[0] = make_float4(vals[0], vals[1], vals[2], vals[3]);
    st[1] = make_float4(vals[4], vals[5], vals[6], vals[7]);
    st[2] = make_float4(vals[8], vals[9], vals[10], vals[11]);
    st[3] = make_float4(vals[12], vals[13], vals[14], vals[15]);
  }
  __syncthreads();

  // ---- phase 1a: aX pass (LL/RR column tcx) ----
  if (KIND < 2) {
    const int tcx = t & 15;
    float aX[16];
#pragma unroll
    for (int l = 0; l < 16; ++l) aX[l] = 0.f;
#pragma unroll 4
    for (int it = 0; it < 16; ++it) {
      const int jl = (t >> 4) + (it << 4);
      const float4* Vw = (const float4*)(ST + jl * 20);
      float4 b0 = Vw[0], b1 = Vw[1], b2 = Vw[2], b3 = Vw[3];
      float xc = ST[jl * 20 + tcx];
      aX[0]  += b0.x * xc; aX[1]  += b0.y * xc; aX[2]  += b0.z * xc; aX[3]  += b0.w * xc;
      aX[4]  += b1.x * xc; aX[5]  += b1.y * xc; aX[6]  += b1.z * xc; aX[7]  += b1.w * xc;
      aX[8]  += b2.x * xc; aX[9]  += b2.y * xc; aX[10] += b2.z * xc; aX[11] += b2.w * xc;
      aX[12] += b3.x * xc; aX[13] += b3.y * xc; aX[14] += b3.z * xc; aX[15] += b3.w * xc;
    }
#pragma unroll
    for (int l = 0; l < 16; ++l) {
      float v = aX[l];
      v += __shfl_xor(v, 16); v += __shfl_xor(v, 32);
      aX[l] = v;
    }
    if (lane < 16) {
      float* p = RDs + w * 288 + lane * 17;
#pragma unroll
      for (int l = 0; l < 16; ++l) p[l] = aX[l];
    }
  }

  // ---- phase 1b: aN pass (row sums) ----
  if (KIND >= 1) {
    float aN[16];
#pragma unroll
    for (int l = 0; l < 16; ++l) aN[l] = 0.f;
#pragma unroll 4
    for (int it = 0; it < 16; ++it) {
      const int jl = (t >> 4) + (it << 4);
      const float4* Vw = (const float4*)(ST + jl * 20);
      float4 b0 = Vw[0], b1 = Vw[1], b2 = Vw[2], b3 = Vw[3];
      aN[0]  += b0.x; aN[1]  += b0.y; aN[2]  += b0.z; aN[3]  += b0.w;
      aN[4]  += b1.x; aN[5]  += b1.y; aN[6]  += b1.z; aN[7]  += b1.w;
      aN[8]  += b2.x; aN[9]  += b2.y; aN[10] += b2.z; aN[11] += b2.w;
      aN[12] += b3.x; aN[13] += b3.y; aN[14] += b3.z; aN[15] += b3.w;
    }
#pragma unroll
    for (int l = 0; l < 16; ++l) {
      float v = aN[l];
      v += __shfl_xor(v, 16); v += __shfl_xor(v, 32);
      aN[l] = v;
    }
    if (lane == 0) {
      float* p = RDs + w * 288 + 272;
#pragma unroll
      for (int l = 0; l < 16; ++l) p[l] = aN[l];
    }
  }

  // ---- phase 2: main pair loop ----
  float aQ0[16], aQ1[16];
#pragma unroll
  for (int l = 0; l < 16; ++l) { aQ0[l] = 0.f; aQ1[l] = 0.f; }
  {
    const int p2 = t & 31, slot8 = t >> 5;
    const float* srow = sb + (size_t)jbase * D_ + (p2 << 1);
#pragma unroll 4
    for (int it = 0; it < 32; ++it) {
      const int jl = slot8 + (it << 3);
      const float4* Vw = (const float4*)(ST + jl * 20);
      float4 b0 = Vw[0], b1 = Vw[1], b2 = Vw[2], b3 = Vw[3];
      float2 qq = *(const float2*)(srow + (size_t)jl * D_);
      aQ0[0]  += qq.x * b0.x; aQ1[0]  += qq.y * b0.x;
      aQ0[1]  += qq.x * b0.y; aQ1[1]  += qq.y * b0.y;
      aQ0[2]  += qq.x * b0.z; aQ1[2]  += qq.y * b0.z;
      aQ0[3]  += qq.x * b0.w; aQ1[3]  += qq.y * b0.w;
      aQ0[4]  += qq.x * b1.x; aQ1[4]  += qq.y * b1.x;
      aQ0[5]  += qq.x * b1.y; aQ1[5]  += qq.y * b1.y;
      aQ0[6]  += qq.x * b1.z; aQ1[6]  += qq.y * b1.z;
      aQ0[7]  += qq.x * b1.w; aQ1[7]  += qq.y * b1.w;
      aQ0[8]  += qq.x * b2.x; aQ1[8]  += qq.y * b2.x;
      aQ0[9]  += qq.x * b2.y; aQ1[9]  += qq.y * b2.y;
      aQ0[10] += qq.x * b2.z; aQ1[10] += qq.y * b2.z;
      aQ0[11] += qq.x * b2.w; aQ1[11] += qq.y * b2.w;
      aQ0[12] += qq.x * b3.x; aQ1[12] += qq.y * b3.x;
      aQ0[13] += qq.x * b3.y; aQ1[13] += qq.y * b3.y;
      aQ0[14] += qq.x * b3.z; aQ1[14] += qq.y * b3.z;
      aQ0[15] += qq.x * b3.w; aQ1[15] += qq.y * b3.w;
    }
  }
#pragma unroll
  for (int l = 0; l < 16; ++l) {
    aQ0[l] += __shfl_xor(aQ0[l], 32);
    aQ1[l] += __shfl_xor(aQ1[l], 32);
  }
  __syncthreads();   // all ST reads done; overlay aQ dump
  if (lane < 32) {
    float* g = B + w * 1056 + lane * 33;
#pragma unroll
    for (int l = 0; l < 16; ++l) { g[l] = aQ0[l]; g[16 + l] = aQ1[l]; }
  }
  __syncthreads();
  // gather LQ: pbase[a*16+l], a = 2*p + c
#pragma unroll
  for (int r = 0; r < 4; ++r) {
    int o = t + r * 256;
    int a = o >> 4, l = o & 15;
    int idx = (a >> 1) * 33 + ((a & 1) << 4) + l;
    pbase[a * 16 + l] = B[idx] + B[1056 + idx] + B[2112 + idx] + B[3168 + idx];
  }
  if (KIND < 2) {
    int c = t >> 4, l = t & 15;
    int idx = 5120 + c * 17 + l;
    pbase[1024 + l * 16 + c] = B[idx] + B[288 + idx] + B[576 + idx] + B[864 + idx];
  }
  if (KIND >= 1 && t < 16) {
    int idx = 5120 + 272 + t;
    pbase[(KIND == 1 ? 1280 : 1024) + t] =
        B[idx] + B[288 + idx] + B[576 + idx] + B[864 + idx];
  }
}

// M: RRS[k][l] (256) + KRT[a*16+l] (1024); ls[] recomputed inline
__device__ __forceinline__ void rowUpdate(const float* M, const float4* q4, float lv[16]) {
  const float4* RR4 = (const float4*)M;
  float n2 = 0.f;
#pragma unroll
  for (int l = 0; l < 16; ++l) n2 += lv[l] * lv[l];
  float ri = rsqrtf(n2);
  float r2 = ri * ri;
  float L[16];
#pragma unroll
  for (int l = 0; l < 16; ++l) L[l] = lv[l] * lv[l] * r2;
  float dl[16];
#pragma unroll
  for (int l = 0; l < 16; ++l) dl[l] = 0.f;
#pragma unroll
  for (int k = 0; k < 16; ++k) {
    float Lk = L[k];
#pragma unroll
    for (int g = 0; g < 4; ++g) {
      float4 rr = RR4[k * 4 + g];
      dl[4*g+0] += Lk * rr.x; dl[4*g+1] += Lk * rr.y;
      dl[4*g+2] += Lk * rr.z; dl[4*g+3] += Lk * rr.w;
    }
  }
#pragma unroll
  for (int a4 = 0; a4 < 16; ++a4) {
    float4 qq = q4[a4];
#pragma unroll
    for (int c = 0; c < 4; ++c) {
      float qa = (c == 0) ? qq.x : (c == 1) ? qq.y : (c == 2) ? qq.z : qq.w;
      const float4* kr = (const float4*)(M + 256 + (a4 * 4 + c) * 16);
#pragma unroll
      for (int g = 0; g < 4; ++g) {
        float4 k4 = kr[g];
        dl[4*g+0] -= qa * k4.x; dl[4*g+1] -= qa * k4.y;
        dl[4*g+2] -= qa * k4.z; dl[4*g+3] -= qa * k4.w;
      }
    }
  }
  float dot = 0.f;
#pragma unroll
  for (int l = 0; l < 16; ++l) {
    float lsl = lv[l] * ri;
    dl[l] *= lsl;
    dot += lsl * dl[l];
  }
#pragma unroll
  for (int l = 0; l < 16; ++l) {
    float lsl = lv[l] * ri;
    lv[l] -= STEPSZ * (dl[l] - lsl * dot) * ri;
  }
}

// M: MLL (256) + MLQT[a*16+k] (1024); C: C1(16), C2(16), SRN(16)
__device__ __forceinline__ void colUpdate(const float* M, const float* C,
                                          const float4* k4, float nv[16]) {
  const float4* MLL4 = (const float4*)M;
  const float* C1 = C;
  const float* C2 = C + 16;
  const float* SRN = C + 32;
  float rp2[16];
#pragma unroll
  for (int l = 0; l < 16; ++l) rp2[l] = nv[l] * nv[l];
  float s[16];
#pragma unroll
  for (int k = 0; k < 16; ++k) {
    float a0 = 0.f;
#pragma unroll
    for (int g = 0; g < 4; ++g) {
      float4 m = MLL4[k * 4 + g];
      a0 += m.x * rp2[4*g+0] + m.y * rp2[4*g+1] + m.z * rp2[4*g+2] + m.w * rp2[4*g+3];
    }
    s[k] = a0;
  }
#pragma unroll
  for (int a4 = 0; a4 < 16; ++a4) {
    float4 kk = k4[a4];
#pragma unroll
    for (int c = 0; c < 4; ++c) {
      float ka = (c == 0) ? kk.x : (c == 1) ? kk.y : (c == 2) ? kk.z : kk.w;
      const float4* mq = (const float4*)(M + 256 + (a4 * 4 + c) * 16);
#pragma unroll
      for (int g = 0; g < 4; ++g) {
        float4 m = mq[g];
        s[4*g+0] -= ka * m.x; s[4*g+1] -= ka * m.y;
        s[4*g+2] -= ka * m.z; s[4*g+3] -= ka * m.w;
      }
    }
  }
#pragma unroll
  for (int k = 0; k < 16; ++k) {
    float rs = nv[k] * SRN[k];
    float d2 = rs * s[k];
    nv[k] = C1[k] * nv[k] - C2[k] * d2;
  }
}

// ---------------------------------------------------------------------------
// kStep<MODE>: grid (32, BH_, 2), 256-row tiles (R11 shell, no forced bounds).
// z=0 row side (lp, q); z=1 col side (rp, key / v when MODE==2).
// ---------------------------------------------------------------------------
template <int MODE>
__global__ void __launch_bounds__(256) kStep(const float* __restrict__ accF,
                                             const float* __restrict__ q,
                                             const float* __restrict__ key,
                                             const float* __restrict__ vv,
                                             const float* __restrict__ lp0,
                                             const float* __restrict__ rp0,
                                             float* __restrict__ lp,
                                             float* __restrict__ rp,
                                             float* __restrict__ part,
                                             float* __restrict__ part2) {
  const int bh = blockIdx.y, bx = blockIdx.x, t = threadIdx.x;
  const int j0 = bx * 256, j = j0 + t;
  const int bb = bh * 32 + bx;
  __shared__ float B[6400];
  const float* A = accF + (size_t)bh * ACCF_STRIDE;
  const float* qb = q + (size_t)bh * S_ * D_;
  const float* kb = key + (size_t)bh * S_ * D_;
  const size_t base = ((size_t)bh * S_ + j) * 16;

  if (blockIdx.z == 0) {
    float lv[16];
    const float4* s4 = (const float4*)((MODE == 0 ? lp0 : lp) + base);
    float4 a0 = s4[0], a1 = s4[1], a2 = s4[2], a3 = s4[3];
    lv[0]=a0.x; lv[1]=a0.y; lv[2]=a0.z; lv[3]=a0.w;
    lv[4]=a1.x; lv[5]=a1.y; lv[6]=a1.z; lv[7]=a1.w;
    lv[8]=a2.x; lv[9]=a2.y; lv[10]=a2.z; lv[11]=a2.w;
    lv[12]=a3.x; lv[13]=a3.y; lv[14]=a3.z; lv[15]=a3.w;
    if (MODE >= 1) {
      for (int e = t; e < 1280; e += 256) B[e] = A[1280 + e];  // RRS + KRT
      __syncthreads();
      rowUpdate(B, (const float4*)(qb + (size_t)j * D_), lv);
      __syncthreads();  // matrices consumed before stage overwrites B
    }
    {
      float4* d4 = (float4*)(lp + base);
      d4[0] = make_float4(lv[0], lv[1], lv[2], lv[3]);
      d4[1] = make_float4(lv[4], lv[5], lv[6], lv[7]);
      d4[2] = make_float4(lv[8], lv[9], lv[10], lv[11]);
      d4[3] = make_float4(lv[12], lv[13], lv[14], lv[15]);
    }
    if (MODE == 2) return;
    float L[16];
    {
      float m2 = 0.f;
#pragma unroll
      for (int l = 0; l < 16; ++l) m2 += lv[l] * lv[l];
      float r2 = 1.0f / m2;
#pragma unroll
      for (int l = 0; l < 16; ++l) L[l] = lv[l] * lv[l] * r2;
    }
    reduceSide<0>(qb, j0, t, L, B, part + (size_t)bb * PART_STRIDE);
  } else {
    float nv[16];
    if (MODE == 0) {
      const float* rsrc = rp0 + (size_t)bh * 16 * S_ + j;   // original [r][S]
#pragma unroll
      for (int k = 0; k < 16; ++k) nv[k] = rsrc[(size_t)k * S_];
    } else {
      const float4* r4 = (const float4*)(rp + base);        // internal [i][16]
      float4 a0 = r4[0], a1 = r4[1], a2 = r4[2], a3 = r4[3];
      nv[0]=a0.x; nv[1]=a0.y; nv[2]=a0.z; nv[3]=a0.w;
      nv[4]=a1.x; nv[5]=a1.y; nv[6]=a1.z; nv[7]=a1.w;
      nv[8]=a2.x; nv[9]=a2.y; nv[10]=a2.z; nv[11]=a2.w;
      nv[12]=a3.x; nv[13]=a3.y; nv[14]=a3.z; nv[15]=a3.w;
      for (int e = t; e < 1328; e += 256) B[e] = (e < 1280) ? A[e] : A[1280 + e];
      __syncthreads();
      colUpdate(B, B + 1280, (const float4*)(kb + (size_t)j * D_), nv);
      __syncthreads();  // matrices consumed
    }
    {
      float4* d4 = (float4*)(rp + base);
      d4[0] = make_float4(nv[0], nv[1], nv[2], nv[3]);
      d4[1] = make_float4(nv[4], nv[5], nv[6], nv[7]);
      d4[2] = make_float4(nv[8], nv[9], nv[10], nv[11]);
      d4[3] = make_float4(nv[12], nv[13], nv[14], nv[15]);
    }
    float rp2[16];
#pragma unroll
    for (int l = 0; l < 16; ++l) rp2[l] = nv[l] * nv[l];
    if (MODE < 2)
      reduceSide<1>(kb, j0, t, rp2, B, part + (size_t)bb * PART_STRIDE + 1280);
    else
      reduceSide<2>(vv + (size_t)bh * S_ * D_, j0, t, rp2, B,
                    part2 + (size_t)bb * PART2_STRIDE);
  }
}

// ---------------------------------------------------------------------------
// kB: one block per bh. Sum 32 partials -> derived matrices + analytic PJ, c1/c2.
// ---------------------------------------------------------------------------
__global__ void __launch_bounds__(256) kB(const float* __restrict__ part,
                                          float* __restrict__ accF) {
  const int bh = blockIdx.x, t = threadIdx.x;
  __shared__ float raw[PART_STRIDE];
  __shared__ float inn[16], srn[16];
  const float* p0 = part + (size_t)bh * 32 * PART_STRIDE;
  for (int vI = t; vI < PART_STRIDE; vI += 256) {
    float s = 0.f;
    const float* p = p0 + vI;
#pragma unroll 8
    for (int b2 = 0; b2 < 32; ++b2) s += p[(size_t)b2 * PART_STRIDE];
    raw[vI] = s;
  }
  __syncthreads();
  if (t < 16) {
    float N = raw[2560 + t];
    inn[t] = 1.0f / N;
    srn[t] = rsqrtf(N);
  }
  __syncthreads();
  float* o = accF + (size_t)bh * ACCF_STRIDE;
  o[t] = raw[1024 + t] * CC * inn[t & 15];                        // MLL[k][l]
  o[1280 + t] = raw[2304 + t] * CC * inn[t >> 4] * inn[t & 15];   // RRS[k][l]
#pragma unroll
  for (int r = 0; r < 4; ++r) {
    int e = t + r * 256;
    o[256 + e] = raw[e] * CC;                                     // MLQT[a*16+k]
  }
#pragma unroll
  for (int r = 0; r < 4; ++r) {
    int e = t + r * 256;
    o[1536 + e] = raw[1280 + e] * CC * inn[e & 15];               // KRT[a*16+l]
  }
  if (t < 16) {
    int k = t;
    float s = 0.f;
#pragma unroll
    for (int l = 0; l < 16; ++l)
      s += raw[1024 + k * 16 + l] * CC * inn[l] * raw[2304 + k * 16 + l];
#pragma unroll
    for (int a = 0; a < 64; ++a)
      s -= raw[a * 16 + k] * CC * raw[1280 + a * 16 + k];
    float PJ = inn[k] * s;
    o[2560 + t] = 1.0f + STEPSZ * PJ * inn[t];
    o[2576 + t] = STEPSZ * srn[t];
    o[2592 + t] = srn[t];
  }
}

__global__ void __launch_bounds__(256) kBF(const float* __restrict__ part2,
                                           float* __restrict__ RVs) {
  const int bh = blockIdx.x, t = threadIdx.x;
  __shared__ float raw[PART2_STRIDE];
  __shared__ float inn[16];
  const float* p0 = part2 + (size_t)bh * 32 * PART2_STRIDE;
  for (int vI = t; vI < PART2_STRIDE; vI += 256) {
    float s = 0.f;
    const float* p = p0 + vI;
#pragma unroll 8
    for (int b2 = 0; b2 < 32; ++b2) s += p[(size_t)b2 * PART2_STRIDE];
    raw[vI] = s;
  }
  __syncthreads();
  if (t < 16) inn[t] = 1.0f / raw[1024 + t];
  __syncthreads();
#pragma unroll
  for (int r = 0; r < 4; ++r) {
    int e = t + r * 256;  // e = k*64+d ; RV raw at [d*16+k]
    RVs[(size_t)bh * 1024 + e] = raw[((e & 63) << 4) + (e >> 6)] * inn[e >> 6];
  }
}

// out[j][d] = sum_k unit(lp_j)^2[k] * RVs[bh][k][d]
__global__ void __launch_bounds__(256) kOut(const float* __restrict__ lp,
                                            const float* __restrict__ RVs,
                                            float* __restrict__ out) {
  const int bh = blockIdx.y, t = threadIdx.x;
  __shared__ float rvs[1024];
#pragma unroll
  for (int r = 0; r < 4; ++r) rvs[t + r * 256] = RVs[(size_t)bh * 1024 + t + r * 256];
  __syncthreads();
  const int j = blockIdx.x * 256 + t;
  size_t base = ((size_t)bh * S_ + j) * 16;
  const float4* lp4 = (const float4*)(lp + base);
  float4 a0 = lp4[0], a1 = lp4[1], a2 = lp4[2], a3 = lp4[3];
  float lv[16] = {a0.x,a0.y,a0.z,a0.w, a1.x,a1.y,a1.z,a1.w,
                  a2.x,a2.y,a2.z,a2.w, a3.x,a3.y,a3.z,a3.w};
  float n2 = 0.f;
#pragma unroll
  for (int l = 0; l < 16; ++l) n2 += lv[l] * lv[l];
  float r2 = 1.0f / n2;
  float L[16];
#pragma unroll
  for (int l = 0; l < 16; ++l) L[l] = lv[l] * lv[l] * r2;
  float o[64];
#pragma unroll
  for (int d = 0; d < 64; ++d) o[d] = 0.f;
  const float4* rv4 = (const float4*)rvs;
#pragma unroll
  for (int k = 0; k < 16; ++k) {
    float Lk = L[k];
#pragma unroll
    for (int d4 = 0; d4 < 16; ++d4) {
      float4 r = rv4[k * 16 + d4];
      o[4*d4+0] += Lk * r.x; o[4*d4+1] += Lk * r.y;
      o[4*d4+2] += Lk * r.z; o[4*d4+3] += Lk * r.w;
    }
  }
  float4* o4 = (float4*)(out + ((size_t)bh * S_ + j) * D_);
#pragma unroll
  for (int d4 = 0; d4 < 16; ++d4)
    o4[d4] = make_float4(o[4*d4+0], o[4*d4+1], o[4*d4+2], o[4*d4+3]);
}

extern "C" void kernel_launch(void* const* d_in, const int* in_sizes, int n_in,
                              void* d_out, int out_size, void* d_ws, size_t ws_size,
                              hipStream_t stream) {
  (void)in_sizes; (void)n_in; (void)out_size; (void)ws_size;
  const float* q = (const float*)d_in[0];
  const float* key = (const float*)d_in[1];
  const float* v = (const float*)d_in[2];
  const float* lp0 = (const float*)d_in[3];
  const float* rp0 = (const float*)d_in[4];
  float* out = (float*)d_out;
  float* ws = (float*)d_ws;

  float* lp = ws;                  // 3,145,728 floats ([j][16])
  float* rp = lp + LP_N;           // 3,145,728 ([i][16] internal)
  float* part = rp + LP_N;         // 1,978,368
  float* accF = part + PART_N;     // 62,976
  float* part2 = accF + ACCF_N;    // 798,720
  float* RVs = part2 + PART2_N;    // 24,576
  // total 9,156,096 floats = 36.6 MB

  dim3 blk(256);
  dim3 gS(32, BH_, 2);
  kStep<0><<<gS, blk, 0, stream>>>(accF, q, key, v, lp0, rp0, lp, rp, part, part2);
  for (int s = 0; s < 10; ++s) {
    kB<<<dim3(BH_), blk, 0, stream>>>(part, accF);
    if (s < 9)
      kStep<1><<<gS, blk, 0, stream>>>(accF, q, key, v, lp0, rp0, lp, rp, part, part2);
    else
      kStep<2><<<gS, blk, 0, stream>>>(accF, q, key, v, lp0, rp0, lp, rp, part, part2);
  }
  kBF<<<dim3(BH_), blk, 0, stream>>>(part2, RVs);
  kOut<<<dim3(32, BH_), blk, 0, stream>>>(lp, RVs, out);
}